// Round 12
// baseline (206.417 us; speedup 1.0000x reference)
//
#include <hip/hip_runtime.h>
#include <cstdint>
#include <cstddef>

typedef _Float16 h8_t __attribute__((ext_vector_type(8)));
typedef _Float16 h4_t __attribute__((ext_vector_type(4)));
typedef float f32x4 __attribute__((ext_vector_type(4)));
typedef float f32x16 __attribute__((ext_vector_type(16)));
typedef unsigned u32x4 __attribute__((ext_vector_type(4)));

#define MFMA_16x16x32_F16(a, b, c) __builtin_amdgcn_mfma_f32_16x16x32_f16(a, b, c, 0, 0, 0)
#define MFMA_32x32x16_F16(a, b, c) __builtin_amdgcn_mfma_f32_32x32x16_f16(a, b, c, 0, 0, 0)

__device__ inline void gload_lds16(const void* g, void* l) {
  __builtin_amdgcn_global_load_lds((const __attribute__((address_space(1))) void*)g,
                                   (__attribute__((address_space(3))) void*)l, 16, 0, 0);
}

#define CFENCE asm volatile("" ::: "memory")
#define RAW_BAR() do { CFENCE; __builtin_amdgcn_s_barrier(); CFENCE; } while (0)

// ---------------- fused weight transposes: w_qkv (1024x3072) and w_out (1024x1024) -------
__global__ void prep_kernel(const float* __restrict__ wqkv, _Float16* __restrict__ wqkvT,
                            const float* __restrict__ wout, _Float16* __restrict__ woutT) {
  __shared__ float tile[32][33];
  int blk = blockIdx.x;
  const float* src;
  _Float16* dst;
  int Cc, cb, rb;
  if (blk < 3072) { src = wqkv; dst = wqkvT; Cc = 3072; cb = blk % 96; rb = blk / 96; }
  else { blk -= 3072; src = wout; dst = woutT; Cc = 1024; cb = blk & 31; rb = blk >> 5; }
  const int R = 1024;
  int tx = threadIdx.x & 31;
  int ty = threadIdx.x >> 5;
  int c0 = cb * 32, r0 = rb * 32;
#pragma unroll
  for (int i = 0; i < 4; ++i)
    tile[ty + i * 8][tx] = src[(size_t)(r0 + ty + i * 8) * Cc + (c0 + tx)];
  __syncthreads();
#pragma unroll
  for (int i = 0; i < 4; ++i)
    dst[(size_t)(c0 + ty + i * 8) * R + (r0 + tx)] = (_Float16)tile[tx][ty + i * 8];
}

// ============ QKV GEMM: 256x384, 8 waves, 2-phase/K-tile, triple-buffer, FUSED f32->f16 ===
// A (= x) is read in f32 and reg-staged (T14): 4 global_load_dwordx4 issued at iter top
// (inline asm, pinned order), drained by the end-of-iter counted vmcnt(3) (A(t+2)+B(t+1)
// done, B(t+2) in flight), converted (RTN casts) and ds_written before the barrier.
// Write(t+2) vs last read(t-1) separated by the end-of-(t-1) barrier. B stays global_load_lds.
__global__ __launch_bounds__(512, 2) void gemm_qkv_kernel(
    const float* __restrict__ X, const _Float16* __restrict__ Bt,
    const float* __restrict__ bias, _Float16* __restrict__ outQ,
    _Float16* __restrict__ outK, _Float16* __restrict__ outV) {
  __shared__ _Float16 Al[3][8192];   // 256x32 f16, fragment-major
  __shared__ _Float16 Bl[3][12288];  // 384x32 f16

  const int tid = threadIdx.x;
  const int lane = tid & 63;
  const int w = tid >> 6;
  const int wm = w >> 2, wn = w & 3;
  const int bm = blockIdx.x >> 3;
  const int bn = blockIdx.x & 7;
  const int m0 = bm * 256;
  const int n0 = bn * 384;

  f32x4 acc[8][6];
#pragma unroll
  for (int i = 0; i < 8; ++i)
#pragma unroll
    for (int j = 0; j < 6; ++j) acc[i][j] = (f32x4){0.f, 0.f, 0.f, 0.f};

  const int fg0 = tid >> 6;
  const int sl = tid & 63;
  const int srow = fg0 * 16 + (sl & 15);
  const int scol = (sl >> 4) * 8;
  const float* aS0 = X + (size_t)(m0 + srow) * 1024 + scol;   // unit 0 (rows 0..127)
  const float* aS1 = aS0 + 131072;                            // unit 1 (rows 128..255)
  const _Float16* bS = Bt + (size_t)(n0 + srow) * 1024 + scol;
  const int sdst = tid * 8;

  f32x4 ar0, ar1, ar2, ar3;  // staged A f32 (unit0 lo/hi, unit1 lo/hi)

  auto issueA = [&](int kt) {
    const float* p0 = aS0 + kt * 32;
    const float* p1 = aS1 + kt * 32;
    asm volatile(
        "global_load_dwordx4 %0, %4, off\n\t"
        "global_load_dwordx4 %1, %4, off offset:16\n\t"
        "global_load_dwordx4 %2, %5, off\n\t"
        "global_load_dwordx4 %3, %5, off offset:16"
        : "=&v"(ar0), "=&v"(ar1), "=&v"(ar2), "=&v"(ar3)
        : "v"(p0), "v"(p1)
        : "memory");
  };
  auto writeA = [&](int buf) {
    h8_t h0, h1;
#pragma unroll
    for (int i = 0; i < 4; ++i) {
      h0[i] = (_Float16)ar0[i]; h0[4 + i] = (_Float16)ar1[i];
      h1[i] = (_Float16)ar2[i]; h1[4 + i] = (_Float16)ar3[i];
    }
    *reinterpret_cast<h8_t*>(&Al[buf][sdst]) = h0;
    *reinterpret_cast<h8_t*>(&Al[buf][sdst + 4096]) = h1;
  };
  auto stageB = [&](int buf, int kt) {
    const int k0 = kt * 32;
    gload_lds16(bS + k0, &Bl[buf][sdst]);
    gload_lds16(bS + 131072 + k0, &Bl[buf][sdst + 4096]);
    gload_lds16(bS + 262144 + k0, &Bl[buf][sdst + 8192]);
  };

  const int offA0 = (wm * 8 * 64 + lane) * 8;
  const int offB0 = (wn * 6 * 64 + lane) * 8;

  // prologue: tiles 0,1. vmcnt bookkeeping: A=4 loads, B=3 loads per tile.
  issueA(0);                                   // A0(4)
  stageB(0, 0);                                // +B0(3) = 7
  asm volatile("s_waitcnt vmcnt(3)" ::: "memory");  // A0 done
  __builtin_amdgcn_sched_barrier(0);
  writeA(0);
  issueA(1);                                   // B0(3)+A1(4) = 7
  stageB(1, 1);                                // +B1(3) = 10
  asm volatile("s_waitcnt vmcnt(3)" ::: "memory");  // B0,A1 done; B1 in flight
  __builtin_amdgcn_sched_barrier(0);
  writeA(1);
  asm volatile("s_waitcnt lgkmcnt(0)" ::: "memory");
  RAW_BAR();

  int cur = 0;
#pragma unroll 1
  for (int t = 0; t < 32; ++t) {
    int nb = cur + 2; if (nb >= 3) nb -= 3;
    const bool st = (t + 2) < 32;
    const _Float16* Ab = &Al[cur][0];
    const _Float16* Bb = &Bl[cur][0];
    h8_t af[4], bf[6];

    // iter top: issue next-next tile's loads (A globals + B lds-DMA)
    if (st) { issueA(t + 2); stageB(nb, t + 2); }

    // ---- phase 0: A-frags 0..3 + all B-frags; MFMA m0..3 x n0..5
#pragma unroll
    for (int mf = 0; mf < 4; ++mf) af[mf] = *(const h8_t*)&Ab[offA0 + mf * 512];
#pragma unroll
    for (int nf = 0; nf < 6; ++nf) bf[nf] = *(const h8_t*)&Bb[offB0 + nf * 512];
    asm volatile("s_waitcnt lgkmcnt(0)" ::: "memory");
    __builtin_amdgcn_sched_barrier(0);
    __builtin_amdgcn_s_setprio(1);
#pragma unroll
    for (int mf = 0; mf < 4; ++mf)
#pragma unroll
      for (int nf = 0; nf < 6; ++nf)
        acc[mf][nf] = MFMA_16x16x32_F16(af[mf], bf[nf], acc[mf][nf]);
    __builtin_amdgcn_s_setprio(0);

    // ---- phase 1: A-frags 4..7; MFMA m4..7 x n0..5
#pragma unroll
    for (int mf = 0; mf < 4; ++mf) af[mf] = *(const h8_t*)&Ab[offA0 + (4 + mf) * 512];
    asm volatile("s_waitcnt lgkmcnt(0)" ::: "memory");
    __builtin_amdgcn_sched_barrier(0);
    __builtin_amdgcn_s_setprio(1);
#pragma unroll
    for (int mf = 0; mf < 4; ++mf)
#pragma unroll
      for (int nf = 0; nf < 6; ++nf)
        acc[4 + mf][nf] = MFMA_16x16x32_F16(af[mf], bf[nf], acc[4 + mf][nf]);
    __builtin_amdgcn_s_setprio(0);

    // ---- iter end: counted drain, convert+write A(t+2), publish
    if (t < 31) {
      if (st) {
        // outstanding: B(t+1)=3 oldest, A(t+2)=4, B(t+2)=3 newest -> vmcnt(3)
        asm volatile("s_waitcnt vmcnt(3)" ::: "memory");
        __builtin_amdgcn_sched_barrier(0);
        writeA(nb);
      } else {
        asm volatile("s_waitcnt vmcnt(0)" ::: "memory");
      }
      asm volatile("s_waitcnt lgkmcnt(0)" ::: "memory");
      RAW_BAR();
    }
    ++cur; if (cur == 3) cur = 0;
  }

  // ---- epilogue: route Q (scaled, exp2-ready), K, V^T
  const int gm0 = m0 + wm * 128;
  const int gn0 = n0 + wn * 96;
#pragma unroll
  for (int mf = 0; mf < 8; ++mf) {
#pragma unroll
    for (int nf = 0; nf < 6; ++nf) {
      const int gn = gn0 + nf * 16 + (lane & 15);
      const int tm0 = gm0 + mf * 16 + (lane >> 4) * 4;
      const float bv = bias[gn];
      const int which = gn >> 10;  // 0=Q 1=K 2=V
      const int nn = gn & 1023;
      const int h = nn >> 6, d = nn & 63;
      const int t0 = tm0 & 2047, b = tm0 >> 11;
      const int bh = b * 16 + h;
      if (which == 2) {
        h4_t pack;
#pragma unroll
        for (int r = 0; r < 4; ++r) pack[r] = (_Float16)(acc[mf][nf][r] + bv);
        *reinterpret_cast<h4_t*>(&outV[((size_t)bh * 64 + d) * 2048 + t0]) = pack;
      } else {
        _Float16* dst = (which == 0) ? outQ : outK;
        // Q pre-scaled by log2(e)/sqrt(D) so attention can use exp2 directly
        const float scale = (which == 0) ? 0.18033688011112042f : 1.0f;
#pragma unroll
        for (int r = 0; r < 4; ++r)
          dst[((size_t)bh * 2048 + t0 + r) * 64 + d] = (_Float16)((acc[mf][nf][r] + bv) * scale);
      }
    }
  }
}

// ---------------- out-proj GEMM (R8-proven) ----------------
__global__ __launch_bounds__(256, 3) void gemm_out_kernel(
    const _Float16* __restrict__ A, const _Float16* __restrict__ Bt,
    const float* __restrict__ bias, float* __restrict__ outF, int NB) {
  __shared__ _Float16 Al[3][4096];
  __shared__ _Float16 Bl[3][4096];
  const int tid = threadIdx.x;
  const int lane = tid & 63;
  const int w = tid >> 6;
  const int bm = blockIdx.x / NB;
  const int bn = blockIdx.x % NB;
  const int wm = w & 1, wn = w >> 1;
  const int m0 = bm * 128, n0 = bn * 128;

  f32x4 acc[4][4];
#pragma unroll
  for (int m = 0; m < 4; ++m)
#pragma unroll
    for (int n = 0; n < 4; ++n) acc[m][n] = (f32x4){0.f, 0.f, 0.f, 0.f};

  const int seg0 = w * 2, seg1 = w * 2 + 1;
  const int r0s = seg0 * 16 + (lane >> 2);
  const int r1s = seg1 * 16 + (lane >> 2);
  const int c0s = ((lane & 3) ^ ((r0s >> 1) & 3)) * 8;
  const int c1s = ((lane & 3) ^ ((r1s >> 1) & 3)) * 8;
  const _Float16* aS0 = A + (size_t)(m0 + r0s) * 1024 + c0s;
  const _Float16* aS1 = A + (size_t)(m0 + r1s) * 1024 + c1s;
  const _Float16* bS0 = Bt + (size_t)(n0 + r0s) * 1024 + c0s;
  const _Float16* bS1 = Bt + (size_t)(n0 + r1s) * 1024 + c1s;
  const int d0 = seg0 * 512 + lane * 8;
  const int d1 = seg1 * 512 + lane * 8;

  auto stage = [&](int buf, int kt) {
    const int k0 = kt * 32;
    gload_lds16(aS0 + k0, &Al[buf][d0]);
    gload_lds16(bS0 + k0, &Bl[buf][d0]);
    gload_lds16(aS1 + k0, &Al[buf][d1]);
    gload_lds16(bS1 + k0, &Bl[buf][d1]);
  };

  int offA[4], offB[4];
#pragma unroll
  for (int i = 0; i < 4; ++i) {
    const int rowA = wm * 64 + i * 16 + (lane & 15);
    offA[i] = rowA * 32 + (((lane >> 4) ^ ((rowA >> 1) & 3)) * 8);
    const int rowB = wn * 64 + i * 16 + (lane & 15);
    offB[i] = rowB * 32 + (((lane >> 4) ^ ((rowB >> 1) & 3)) * 8);
  }

  stage(0, 0);
  stage(1, 1);
  asm volatile("s_waitcnt vmcnt(4)" ::: "memory");
  RAW_BAR();

  int cur = 0;
#pragma unroll 1
  for (int t = 0; t < 32; ++t) {
    int nb = cur + 2; if (nb >= 3) nb -= 3;
    if (t + 2 < 32) stage(nb, t + 2);
    const _Float16* Ab = &Al[cur][0];
    const _Float16* Bb = &Bl[cur][0];
    h8_t af[4], bf[4];
#pragma unroll
    for (int i = 0; i < 4; ++i) af[i] = *(const h8_t*)&Ab[offA[i]];
#pragma unroll
    for (int j = 0; j < 4; ++j) bf[j] = *(const h8_t*)&Bb[offB[j]];
#pragma unroll
    for (int i = 0; i < 4; ++i)
#pragma unroll
      for (int j = 0; j < 4; ++j)
        acc[i][j] = MFMA_16x16x32_F16(af[i], bf[j], acc[i][j]);
    if (t < 31) {
      if (t + 2 < 32) asm volatile("s_waitcnt vmcnt(4)" ::: "memory");
      else asm volatile("s_waitcnt vmcnt(0)" ::: "memory");
      RAW_BAR();
    }
    ++cur; if (cur == 3) cur = 0;
  }

  const int gm0 = bm * 128 + wm * 64;
  const int gn0 = bn * 128 + wn * 64;
#pragma unroll
  for (int i = 0; i < 4; ++i) {
#pragma unroll
    for (int j = 0; j < 4; ++j) {
      const int gn = gn0 + j * 16 + (lane & 15);
      const int tm0 = gm0 + i * 16 + (lane >> 4) * 4;
      const float bv = bias[gn];
#pragma unroll
      for (int r = 0; r < 4; ++r)
        outF[(size_t)(tm0 + r) * 1024 + gn] = acc[i][j][r] + bv;
    }
  }
}

// ---------------- flash attention (causal), KVBLK=128, bh-local XCD mapping ----------------
__device__ inline void stage_kv64(const _Float16* __restrict__ Kbh, const _Float16* __restrict__ Vbh,
                                  int kt, _Float16* Kd, _Float16* Vd, int w, int lane) {
  const _Float16* Kg = Kbh + (size_t)kt * 64 * 64;
  const _Float16* Vg = Vbh + kt * 64;
#pragma unroll
  for (int c = 0; c < 2; ++c) {
    const int idx = (2 * w + c) * 64 + lane;
    const int row = idx >> 3;
    const int chs = (idx & 7) ^ (row & 7);  // pre-swizzled global source (T2 via m173)
    gload_lds16(Kg + row * 64 + chs * 8, Kd + idx * 8);
    gload_lds16(Vg + (size_t)row * 2048 + chs * 8, Vd + idx * 8);
  }
}

// pack 16 exp'd f32 into 2 PV B-fragments
__device__ inline void pack_pfrag(const float* e, h8_t* out) {
  unsigned u[8];
#pragma unroll
  for (int i = 0; i < 8; ++i) {
    auto hv = __builtin_amdgcn_cvt_pkrtz(e[2 * i], e[2 * i + 1]);
    u[i] = __builtin_bit_cast(unsigned, hv);
  }
  auto r02 = __builtin_amdgcn_permlane32_swap(u[0], u[2], false, false);
  auto r13 = __builtin_amdgcn_permlane32_swap(u[1], u[3], false, false);
  auto r46 = __builtin_amdgcn_permlane32_swap(u[4], u[6], false, false);
  auto r57 = __builtin_amdgcn_permlane32_swap(u[5], u[7], false, false);
  u32x4 w0 = {(unsigned)r02[0], (unsigned)r13[0], (unsigned)r02[1], (unsigned)r13[1]};
  u32x4 w1 = {(unsigned)r46[0], (unsigned)r57[0], (unsigned)r46[1], (unsigned)r57[1]};
  out[0] = __builtin_bit_cast(h8_t, w0);
  out[1] = __builtin_bit_cast(h8_t, w1);
}

__global__ __launch_bounds__(256, 2) void attn_kernel(
    const _Float16* __restrict__ Q, const _Float16* __restrict__ K,
    const _Float16* __restrict__ Vt, _Float16* __restrict__ O) {
  __shared__ _Float16 Kl[2][2][64 * 64];  // [buf][half]
  __shared__ _Float16 Vl[2][2][64 * 64];
  const int tid = threadIdx.x;
  const int lane = tid & 63;
  const int w = tid >> 6;
  const int hi = lane >> 5;
  const int l31 = lane & 31;
  const int bh = blockIdx.x & 63;   // bh-locality: all pr of a bh share one XCD
  const int pr = blockIdx.x >> 6;
  const int b = bh >> 4, h = bh & 15;
  const _Float16* Kbh = K + (size_t)bh * 2048 * 64;
  const _Float16* Vbh = Vt + (size_t)bh * 64 * 2048;

#pragma unroll
  for (int gi = 0; gi < 2; ++gi) {
    const int g = gi ? (15 - pr) : pr;
    const int nT = g + 1;  // 128-wide KV tiles
    const int qbase = g * 128 + w * 32;
    const int qrow = qbase + l31;

    h8_t qf[4];
    const _Float16* Qp = Q + ((size_t)bh * 2048 + qrow) * 64 + hi * 8;
#pragma unroll
    for (int ds = 0; ds < 4; ++ds)
      qf[ds] = *reinterpret_cast<const h8_t*>(Qp + ds * 16);

    f32x16 oa[2] = {};
    float m = -1e30f, lsum = 0.f;

    stage_kv64(Kbh, Vbh, 0, &Kl[0][0][0], &Vl[0][0][0], w, lane);
    stage_kv64(Kbh, Vbh, 1, &Kl[0][1][0], &Vl[0][1][0], w, lane);
    __syncthreads();

#pragma unroll 1
    for (int T = 0; T < nT; ++T) {
      const int cur = T & 1;
      if (T + 1 < nT) {
        stage_kv64(Kbh, Vbh, 2 * (T + 1), &Kl[cur ^ 1][0][0], &Vl[cur ^ 1][0][0], w, lane);
        stage_kv64(Kbh, Vbh, 2 * (T + 1) + 1, &Kl[cur ^ 1][1][0], &Vl[cur ^ 1][1][0], w, lane);
      }

      const bool diag = (T == g);
      const bool skip1 = diag && (w < 2);  // upper half fully above diagonal for waves 0,1
      f32x16 s[2][2];

      // ---- QK^T (swapped): s[half][sub], col = q = l31, row = k
      __builtin_amdgcn_s_setprio(1);
#pragma unroll
      for (int half = 0; half < 2; ++half) {
        if (half == 1 && skip1) {
#pragma unroll
          for (int r = 0; r < 16; ++r) { s[1][0][r] = -1e30f; s[1][1][r] = -1e30f; }
        } else {
          const char* Kb = (const char*)&Kl[cur][half][0];
          f32x16 a0 = {}, a1 = {};
#pragma unroll
          for (int ds = 0; ds < 4; ++ds) {
            const int bc = ds * 32 + hi * 16;
            h8_t kf0 = *(const h8_t*)(Kb + l31 * 128 + (bc ^ ((l31 & 7) << 4)));
            h8_t kf1 = *(const h8_t*)(Kb + (32 + l31) * 128 + (bc ^ ((l31 & 7) << 4)));
            a0 = MFMA_32x32x16_F16(kf0, qf[ds], a0);
            a1 = MFMA_32x32x16_F16(kf1, qf[ds], a1);
          }
          s[half][0] = a0;
          s[half][1] = a1;
        }
      }
      __builtin_amdgcn_s_setprio(0);
      if (diag) {  // mask k > q within the diagonal 128-tile
#pragma unroll
        for (int half = 0; half < 2; ++half) {
          if (half == 1 && skip1) continue;
#pragma unroll
          for (int r = 0; r < 16; ++r) {
            const int kr = T * 128 + half * 64 + (r & 3) + 8 * (r >> 2) + 4 * hi;
            if (kr > qrow) s[half][0][r] = -1e30f;
            if (kr + 32 > qrow) s[half][1][r] = -1e30f;
          }
        }
      }

      // ---- one softmax pass over 128 cols
      float t[16];
#pragma unroll
      for (int r = 0; r < 16; ++r)
        t[r] = fmaxf(fmaxf(s[0][0][r], s[0][1][r]), fmaxf(s[1][0][r], s[1][1][r]));
#pragma unroll
      for (int st = 8; st >= 1; st >>= 1)
#pragma unroll
        for (int r = 0; r < st; ++r) t[r] = fmaxf(t[r], t[r + st]);
      const float pmax = fmaxf(t[0], __shfl_xor(t[0], 32));
      const float mnew = fmaxf(m, pmax);
      if (__any(mnew > m + 8.f)) {  // defer-max (T13)
        const float al = __builtin_amdgcn_exp2f(m - mnew);
        lsum *= al;
#pragma unroll
        for (int r = 0; r < 16; ++r) { oa[0][r] *= al; oa[1][r] *= al; }
        m = mnew;
      }
      float ps = 0.f;
#pragma unroll
      for (int half = 0; half < 2; ++half)
#pragma unroll
        for (int sub = 0; sub < 2; ++sub)
#pragma unroll
          for (int r = 0; r < 16; ++r) {
            const float pv = __builtin_amdgcn_exp2f(s[half][sub][r] - m);
            s[half][sub][r] = pv;
            ps += pv;
          }
      ps += __shfl_xor(ps, 32);
      lsum += ps;

      // ---- P -> f16 fragments in-register (T12), then PV per half
#pragma unroll
      for (int half = 0; half < 2; ++half) {
        if (half == 1 && skip1) continue;
        h8_t pf[4];
        pack_pfrag((const float*)&s[half][0], pf + 0);
        pack_pfrag((const float*)&s[half][1], pf + 2);
        const char* Vb = (const char*)&Vl[cur][half][0];
        __builtin_amdgcn_s_setprio(1);
#pragma unroll
        for (int dt = 0; dt < 2; ++dt) {
#pragma unroll
          for (int kg = 0; kg < 4; ++kg) {
            const int row = dt * 32 + l31;
            const int bc = kg * 32 + hi * 16;
            h8_t vf = *(const h8_t*)(Vb + row * 128 + (bc ^ ((row & 7) << 4)));
            oa[dt] = MFMA_32x32x16_F16(vf, pf[kg], oa[dt]);
          }
        }
        __builtin_amdgcn_s_setprio(0);
      }
      __syncthreads();
    }

    const float inv = __builtin_amdgcn_rcpf(lsum);
    _Float16* Op = O + ((size_t)b * 2048 + qrow) * 1024 + h * 64;
#pragma unroll
    for (int dt = 0; dt < 2; ++dt) {
#pragma unroll
      for (int rg = 0; rg < 4; ++rg) {
        h4_t pk4;
#pragma unroll
        for (int i = 0; i < 4; ++i) pk4[i] = (_Float16)(oa[dt][rg * 4 + i] * inv);
        *reinterpret_cast<h4_t*>(Op + dt * 32 + rg * 8 + hi * 4) = pk4;
      }
    }
  }
}

extern "C" void kernel_launch(void* const* d_in, const int* in_sizes, int n_in,
                              void* d_out, int out_size, void* d_ws, size_t ws_size,
                              hipStream_t stream) {
  (void)in_sizes; (void)n_in; (void)out_size; (void)ws_size;
  const float* x = (const float*)d_in[0];
  const float* w_qkv = (const float*)d_in[1];
  const float* b_qkv = (const float*)d_in[2];
  const float* w_out = (const float*)d_in[3];
  const float* b_out = (const float*)d_in[4];
  float* out = (float*)d_out;

  char* ws = (char*)d_ws;
  size_t off = 0;
  auto alloc = [&](size_t bytes) {
    void* p = ws + off;
    off += (bytes + 255) & ~(size_t)255;
    return p;
  };
  _Float16* wqkvT = (_Float16*)alloc((size_t)3072 * 1024 * 2);
  _Float16* woutT = (_Float16*)alloc((size_t)1024 * 1024 * 2);
  _Float16* Qh = (_Float16*)alloc((size_t)64 * 2048 * 64 * 2);
  _Float16* Kh = (_Float16*)alloc((size_t)64 * 2048 * 64 * 2);
  _Float16* Vth = (_Float16*)alloc((size_t)64 * 64 * 2048 * 2);
  _Float16* Oh = (_Float16*)alloc((size_t)8192 * 1024 * 2);

  prep_kernel<<<4096, 256, 0, stream>>>(w_qkv, wqkvT, w_out, woutT);
  gemm_qkv_kernel<<<256, 512, 0, stream>>>(x, wqkvT, b_qkv, Qh, Kh, Vth);
  attn_kernel<<<64 * 8, 256, 0, stream>>>(Qh, Kh, Vth, Oh);
  gemm_out_kernel<<<64 * 8, 256, 0, stream>>>(Oh, woutT, b_out, out, 8);
}

// Round 13
// 168.598 us; speedup vs baseline: 1.2243x; 1.2243x over previous
//
#include <hip/hip_runtime.h>
#include <cstdint>
#include <cstddef>

typedef _Float16 h8_t __attribute__((ext_vector_type(8)));
typedef _Float16 h4_t __attribute__((ext_vector_type(4)));
typedef float f32x4 __attribute__((ext_vector_type(4)));
typedef float f32x16 __attribute__((ext_vector_type(16)));
typedef unsigned u32x4 __attribute__((ext_vector_type(4)));

#define MFMA_16x16x32_F16(a, b, c) __builtin_amdgcn_mfma_f32_16x16x32_f16(a, b, c, 0, 0, 0)
#define MFMA_32x32x16_F16(a, b, c) __builtin_amdgcn_mfma_f32_32x32x16_f16(a, b, c, 0, 0, 0)

__device__ inline void gload_lds16(const void* g, void* l) {
  __builtin_amdgcn_global_load_lds((const __attribute__((address_space(1))) void*)g,
                                   (__attribute__((address_space(3))) void*)l, 16, 0, 0);
}

#define CFENCE asm volatile("" ::: "memory")
#define RAW_BAR() do { CFENCE; __builtin_amdgcn_s_barrier(); CFENCE; } while (0)

// ------- fused prep: x f32->f16 (blocks 0..8191), w_qkv^T (..12287), w_out^T (..13311) ----
__global__ void prep_kernel(const float* __restrict__ x, _Float16* __restrict__ x16,
                            const float* __restrict__ wqkv, _Float16* __restrict__ wqkvT,
                            const float* __restrict__ wout, _Float16* __restrict__ woutT) {
  int blk = blockIdx.x;
  if (blk < 8192) {  // cvt: 8192 blocks x 256 threads x 1 float4
    int i = blk * 256 + threadIdx.x;
    float4 v = reinterpret_cast<const float4*>(x)[i];
    h4_t h;
    h[0] = (_Float16)v.x; h[1] = (_Float16)v.y; h[2] = (_Float16)v.z; h[3] = (_Float16)v.w;
    reinterpret_cast<h4_t*>(x16)[i] = h;
    return;
  }
  blk -= 8192;
  __shared__ float tile[32][33];
  const float* src;
  _Float16* dst;
  int Cc, cb, rb;
  if (blk < 3072) { src = wqkv; dst = wqkvT; Cc = 3072; cb = blk % 96; rb = blk / 96; }
  else { blk -= 3072; src = wout; dst = woutT; Cc = 1024; cb = blk & 31; rb = blk >> 5; }
  const int R = 1024;
  int tx = threadIdx.x & 31;
  int ty = threadIdx.x >> 5;
  int c0 = cb * 32, r0 = rb * 32;
#pragma unroll
  for (int i = 0; i < 4; ++i)
    tile[ty + i * 8][tx] = src[(size_t)(r0 + ty + i * 8) * Cc + (c0 + tx)];
  __syncthreads();
#pragma unroll
  for (int i = 0; i < 4; ++i)
    dst[(size_t)(c0 + ty + i * 8) * R + (r0 + tx)] = (_Float16)tile[tx][ty + i * 8];
}

// ============ QKV GEMM (R9/R11-proven): 256x384, 8 waves, 2-phase/K-tile, triple-buffer ===
__global__ __launch_bounds__(512, 2) void gemm_qkv_kernel(
    const _Float16* __restrict__ A, const _Float16* __restrict__ Bt,
    const float* __restrict__ bias, _Float16* __restrict__ outQ,
    _Float16* __restrict__ outK, _Float16* __restrict__ outV) {
  __shared__ _Float16 Al[3][8192];
  __shared__ _Float16 Bl[3][12288];

  const int tid = threadIdx.x;
  const int lane = tid & 63;
  const int w = tid >> 6;
  const int wm = w >> 2, wn = w & 3;
  const int bm = blockIdx.x >> 3;
  const int bn = blockIdx.x & 7;
  const int m0 = bm * 256;
  const int n0 = bn * 384;

  f32x4 acc[8][6];
#pragma unroll
  for (int i = 0; i < 8; ++i)
#pragma unroll
    for (int j = 0; j < 6; ++j) acc[i][j] = (f32x4){0.f, 0.f, 0.f, 0.f};

  const int fg0 = tid >> 6;
  const int sl = tid & 63;
  const int srow = fg0 * 16 + (sl & 15);
  const int scol = (sl >> 4) * 8;
  const _Float16* aS = A + (size_t)(m0 + srow) * 1024 + scol;
  const _Float16* bS = Bt + (size_t)(n0 + srow) * 1024 + scol;
  const int sdst = tid * 8;

  auto stageA = [&](int buf, int kt) {
    const int k0 = kt * 32;
    gload_lds16(aS + k0, &Al[buf][sdst]);
    gload_lds16(aS + 131072 + k0, &Al[buf][sdst + 4096]);
  };
  auto stageB = [&](int buf, int kt) {
    const int k0 = kt * 32;
    gload_lds16(bS + k0, &Bl[buf][sdst]);
    gload_lds16(bS + 131072 + k0, &Bl[buf][sdst + 4096]);
    gload_lds16(bS + 262144 + k0, &Bl[buf][sdst + 8192]);
  };

  const int offA0 = (wm * 8 * 64 + lane) * 8;
  const int offB0 = (wn * 6 * 64 + lane) * 8;

  stageA(0, 0); stageB(0, 0);
  stageA(1, 1); stageB(1, 1);
  asm volatile("s_waitcnt vmcnt(5)" ::: "memory");
  RAW_BAR();

  int cur = 0;
#pragma unroll 1
  for (int t = 0; t < 32; ++t) {
    int nb = cur + 2; if (nb >= 3) nb -= 3;
    const bool st = (t + 2) < 32;
    const _Float16* Ab = &Al[cur][0];
    const _Float16* Bb = &Bl[cur][0];
    h8_t af[4], bf[6];

#pragma unroll
    for (int mf = 0; mf < 4; ++mf) af[mf] = *(const h8_t*)&Ab[offA0 + mf * 512];
#pragma unroll
    for (int nf = 0; nf < 6; ++nf) bf[nf] = *(const h8_t*)&Bb[offB0 + nf * 512];
    if (st) stageA(nb, t + 2);
    RAW_BAR();
    asm volatile("s_waitcnt lgkmcnt(0)" ::: "memory");
    __builtin_amdgcn_sched_barrier(0);
    __builtin_amdgcn_s_setprio(1);
#pragma unroll
    for (int mf = 0; mf < 4; ++mf)
#pragma unroll
      for (int nf = 0; nf < 6; ++nf)
        acc[mf][nf] = MFMA_16x16x32_F16(af[mf], bf[nf], acc[mf][nf]);
    __builtin_amdgcn_s_setprio(0);
    RAW_BAR();

#pragma unroll
    for (int mf = 0; mf < 4; ++mf) af[mf] = *(const h8_t*)&Ab[offA0 + (4 + mf) * 512];
    if (st) stageB(nb, t + 2);
    RAW_BAR();
    asm volatile("s_waitcnt lgkmcnt(0)" ::: "memory");
    __builtin_amdgcn_sched_barrier(0);
    __builtin_amdgcn_s_setprio(1);
#pragma unroll
    for (int mf = 0; mf < 4; ++mf)
#pragma unroll
      for (int nf = 0; nf < 6; ++nf)
        acc[4 + mf][nf] = MFMA_16x16x32_F16(af[mf], bf[nf], acc[4 + mf][nf]);
    __builtin_amdgcn_s_setprio(0);
    if (t < 31) {
      if (st) asm volatile("s_waitcnt vmcnt(5)" ::: "memory");
      else asm volatile("s_waitcnt vmcnt(0)" ::: "memory");
      RAW_BAR();
    }
    ++cur; if (cur == 3) cur = 0;
  }

  const int gm0 = m0 + wm * 128;
  const int gn0 = n0 + wn * 96;
#pragma unroll
  for (int mf = 0; mf < 8; ++mf) {
#pragma unroll
    for (int nf = 0; nf < 6; ++nf) {
      const int gn = gn0 + nf * 16 + (lane & 15);
      const int tm0 = gm0 + mf * 16 + (lane >> 4) * 4;
      const float bv = bias[gn];
      const int which = gn >> 10;  // 0=Q 1=K 2=V
      const int nn = gn & 1023;
      const int h = nn >> 6, d = nn & 63;
      const int t0 = tm0 & 2047, b = tm0 >> 11;
      const int bh = b * 16 + h;
      if (which == 2) {
        h4_t pack;
#pragma unroll
        for (int r = 0; r < 4; ++r) pack[r] = (_Float16)(acc[mf][nf][r] + bv);
        *reinterpret_cast<h4_t*>(&outV[((size_t)bh * 64 + d) * 2048 + t0]) = pack;
      } else {
        _Float16* dst = (which == 0) ? outQ : outK;
        // Q pre-scaled by log2(e)/sqrt(D) so attention can use exp2 directly
        const float scale = (which == 0) ? 0.18033688011112042f : 1.0f;
#pragma unroll
        for (int r = 0; r < 4; ++r)
          dst[((size_t)bh * 2048 + t0 + r) * 64 + d] = (_Float16)((acc[mf][nf][r] + bv) * scale);
      }
    }
  }
}

// ---------------- out-proj GEMM (R8-proven) ----------------
__global__ __launch_bounds__(256, 3) void gemm_out_kernel(
    const _Float16* __restrict__ A, const _Float16* __restrict__ Bt,
    const float* __restrict__ bias, float* __restrict__ outF, int NB) {
  __shared__ _Float16 Al[3][4096];
  __shared__ _Float16 Bl[3][4096];
  const int tid = threadIdx.x;
  const int lane = tid & 63;
  const int w = tid >> 6;
  const int bm = blockIdx.x / NB;
  const int bn = blockIdx.x % NB;
  const int wm = w & 1, wn = w >> 1;
  const int m0 = bm * 128, n0 = bn * 128;

  f32x4 acc[4][4];
#pragma unroll
  for (int m = 0; m < 4; ++m)
#pragma unroll
    for (int n = 0; n < 4; ++n) acc[m][n] = (f32x4){0.f, 0.f, 0.f, 0.f};

  const int seg0 = w * 2, seg1 = w * 2 + 1;
  const int r0s = seg0 * 16 + (lane >> 2);
  const int r1s = seg1 * 16 + (lane >> 2);
  const int c0s = ((lane & 3) ^ ((r0s >> 1) & 3)) * 8;
  const int c1s = ((lane & 3) ^ ((r1s >> 1) & 3)) * 8;
  const _Float16* aS0 = A + (size_t)(m0 + r0s) * 1024 + c0s;
  const _Float16* aS1 = A + (size_t)(m0 + r1s) * 1024 + c1s;
  const _Float16* bS0 = Bt + (size_t)(n0 + r0s) * 1024 + c0s;
  const _Float16* bS1 = Bt + (size_t)(n0 + r1s) * 1024 + c1s;
  const int d0 = seg0 * 512 + lane * 8;
  const int d1 = seg1 * 512 + lane * 8;

  auto stage = [&](int buf, int kt) {
    const int k0 = kt * 32;
    gload_lds16(aS0 + k0, &Al[buf][d0]);
    gload_lds16(bS0 + k0, &Bl[buf][d0]);
    gload_lds16(aS1 + k0, &Al[buf][d1]);
    gload_lds16(bS1 + k0, &Bl[buf][d1]);
  };

  int offA[4], offB[4];
#pragma unroll
  for (int i = 0; i < 4; ++i) {
    const int rowA = wm * 64 + i * 16 + (lane & 15);
    offA[i] = rowA * 32 + (((lane >> 4) ^ ((rowA >> 1) & 3)) * 8);
    const int rowB = wn * 64 + i * 16 + (lane & 15);
    offB[i] = rowB * 32 + (((lane >> 4) ^ ((rowB >> 1) & 3)) * 8);
  }

  stage(0, 0);
  stage(1, 1);
  asm volatile("s_waitcnt vmcnt(4)" ::: "memory");
  RAW_BAR();

  int cur = 0;
#pragma unroll 1
  for (int t = 0; t < 32; ++t) {
    int nb = cur + 2; if (nb >= 3) nb -= 3;
    if (t + 2 < 32) stage(nb, t + 2);
    const _Float16* Ab = &Al[cur][0];
    const _Float16* Bb = &Bl[cur][0];
    h8_t af[4], bf[4];
#pragma unroll
    for (int i = 0; i < 4; ++i) af[i] = *(const h8_t*)&Ab[offA[i]];
#pragma unroll
    for (int j = 0; j < 4; ++j) bf[j] = *(const h8_t*)&Bb[offB[j]];
#pragma unroll
    for (int i = 0; i < 4; ++i)
#pragma unroll
      for (int j = 0; j < 4; ++j)
        acc[i][j] = MFMA_16x16x32_F16(af[i], bf[j], acc[i][j]);
    if (t < 31) {
      if (t + 2 < 32) asm volatile("s_waitcnt vmcnt(4)" ::: "memory");
      else asm volatile("s_waitcnt vmcnt(0)" ::: "memory");
      RAW_BAR();
    }
    ++cur; if (cur == 3) cur = 0;
  }

  const int gm0 = bm * 128 + wm * 64;
  const int gn0 = bn * 128 + wn * 64;
#pragma unroll
  for (int i = 0; i < 4; ++i) {
#pragma unroll
    for (int j = 0; j < 4; ++j) {
      const int gn = gn0 + j * 16 + (lane & 15);
      const int tm0 = gm0 + i * 16 + (lane >> 4) * 4;
      const float bv = bias[gn];
#pragma unroll
      for (int r = 0; r < 4; ++r)
        outF[(size_t)(tm0 + r) * 1024 + gn] = acc[i][j][r] + bv;
    }
  }
}

// ---------------- flash attention (causal), KVBLK=128, bh-local XCD mapping ----------------
__device__ inline void stage_kv64(const _Float16* __restrict__ Kbh, const _Float16* __restrict__ Vbh,
                                  int kt, _Float16* Kd, _Float16* Vd, int w, int lane) {
  const _Float16* Kg = Kbh + (size_t)kt * 64 * 64;
  const _Float16* Vg = Vbh + kt * 64;
#pragma unroll
  for (int c = 0; c < 2; ++c) {
    const int idx = (2 * w + c) * 64 + lane;
    const int row = idx >> 3;
    const int chs = (idx & 7) ^ (row & 7);  // pre-swizzled global source (T2 via m173)
    gload_lds16(Kg + row * 64 + chs * 8, Kd + idx * 8);
    gload_lds16(Vg + (size_t)row * 2048 + chs * 8, Vd + idx * 8);
  }
}

// pack 16 exp'd f32 into 2 PV B-fragments
__device__ inline void pack_pfrag(const float* e, h8_t* out) {
  unsigned u[8];
#pragma unroll
  for (int i = 0; i < 8; ++i) {
    auto hv = __builtin_amdgcn_cvt_pkrtz(e[2 * i], e[2 * i + 1]);
    u[i] = __builtin_bit_cast(unsigned, hv);
  }
  auto r02 = __builtin_amdgcn_permlane32_swap(u[0], u[2], false, false);
  auto r13 = __builtin_amdgcn_permlane32_swap(u[1], u[3], false, false);
  auto r46 = __builtin_amdgcn_permlane32_swap(u[4], u[6], false, false);
  auto r57 = __builtin_amdgcn_permlane32_swap(u[5], u[7], false, false);
  u32x4 w0 = {(unsigned)r02[0], (unsigned)r13[0], (unsigned)r02[1], (unsigned)r13[1]};
  u32x4 w1 = {(unsigned)r46[0], (unsigned)r57[0], (unsigned)r46[1], (unsigned)r57[1]};
  out[0] = __builtin_bit_cast(h8_t, w0);
  out[1] = __builtin_bit_cast(h8_t, w1);
}

__global__ __launch_bounds__(256, 2) void attn_kernel(
    const _Float16* __restrict__ Q, const _Float16* __restrict__ K,
    const _Float16* __restrict__ Vt, _Float16* __restrict__ O) {
  __shared__ _Float16 Kl[2][2][64 * 64];  // [buf][half]
  __shared__ _Float16 Vl[2][2][64 * 64];
  const int tid = threadIdx.x;
  const int lane = tid & 63;
  const int w = tid >> 6;
  const int hi = lane >> 5;
  const int l31 = lane & 31;
  const int bh = blockIdx.x & 63;   // bh-locality: all pr of a bh share one XCD
  const int pr = blockIdx.x >> 6;
  const int b = bh >> 4, h = bh & 15;
  const _Float16* Kbh = K + (size_t)bh * 2048 * 64;
  const _Float16* Vbh = Vt + (size_t)bh * 64 * 2048;

#pragma unroll
  for (int gi = 0; gi < 2; ++gi) {
    const int g = gi ? (15 - pr) : pr;
    const int nT = g + 1;  // 128-wide KV tiles
    const int qbase = g * 128 + w * 32;
    const int qrow = qbase + l31;

    h8_t qf[4];
    const _Float16* Qp = Q + ((size_t)bh * 2048 + qrow) * 64 + hi * 8;
#pragma unroll
    for (int ds = 0; ds < 4; ++ds)
      qf[ds] = *reinterpret_cast<const h8_t*>(Qp + ds * 16);

    f32x16 oa[2] = {};
    float m = -1e30f, lsum = 0.f;

    stage_kv64(Kbh, Vbh, 0, &Kl[0][0][0], &Vl[0][0][0], w, lane);
    stage_kv64(Kbh, Vbh, 1, &Kl[0][1][0], &Vl[0][1][0], w, lane);
    __syncthreads();

#pragma unroll 1
    for (int T = 0; T < nT; ++T) {
      const int cur = T & 1;
      if (T + 1 < nT) {
        stage_kv64(Kbh, Vbh, 2 * (T + 1), &Kl[cur ^ 1][0][0], &Vl[cur ^ 1][0][0], w, lane);
        stage_kv64(Kbh, Vbh, 2 * (T + 1) + 1, &Kl[cur ^ 1][1][0], &Vl[cur ^ 1][1][0], w, lane);
      }

      const bool diag = (T == g);
      const bool skip1 = diag && (w < 2);  // upper half fully above diagonal for waves 0,1
      f32x16 s[2][2];

      // ---- QK^T (swapped): s[half][sub], col = q = l31, row = k
      __builtin_amdgcn_s_setprio(1);
#pragma unroll
      for (int half = 0; half < 2; ++half) {
        if (half == 1 && skip1) {
#pragma unroll
          for (int r = 0; r < 16; ++r) { s[1][0][r] = -1e30f; s[1][1][r] = -1e30f; }
        } else {
          const char* Kb = (const char*)&Kl[cur][half][0];
          f32x16 a0 = {}, a1 = {};
#pragma unroll
          for (int ds = 0; ds < 4; ++ds) {
            const int bc = ds * 32 + hi * 16;
            h8_t kf0 = *(const h8_t*)(Kb + l31 * 128 + (bc ^ ((l31 & 7) << 4)));
            h8_t kf1 = *(const h8_t*)(Kb + (32 + l31) * 128 + (bc ^ ((l31 & 7) << 4)));
            a0 = MFMA_32x32x16_F16(kf0, qf[ds], a0);
            a1 = MFMA_32x32x16_F16(kf1, qf[ds], a1);
          }
          s[half][0] = a0;
          s[half][1] = a1;
        }
      }
      __builtin_amdgcn_s_setprio(0);
      if (diag) {  // mask k > q within the diagonal 128-tile
#pragma unroll
        for (int half = 0; half < 2; ++half) {
          if (half == 1 && skip1) continue;
#pragma unroll
          for (int r = 0; r < 16; ++r) {
            const int kr = T * 128 + half * 64 + (r & 3) + 8 * (r >> 2) + 4 * hi;
            if (kr > qrow) s[half][0][r] = -1e30f;
            if (kr + 32 > qrow) s[half][1][r] = -1e30f;
          }
        }
      }

      // ---- one softmax pass over 128 cols
      float t[16];
#pragma unroll
      for (int r = 0; r < 16; ++r)
        t[r] = fmaxf(fmaxf(s[0][0][r], s[0][1][r]), fmaxf(s[1][0][r], s[1][1][r]));
#pragma unroll
      for (int st = 8; st >= 1; st >>= 1)
#pragma unroll
        for (int r = 0; r < st; ++r) t[r] = fmaxf(t[r], t[r + st]);
      const float pmax = fmaxf(t[0], __shfl_xor(t[0], 32));
      const float mnew = fmaxf(m, pmax);
      if (__any(mnew > m + 8.f)) {  // defer-max (T13)
        const float al = __builtin_amdgcn_exp2f(m - mnew);
        lsum *= al;
#pragma unroll
        for (int r = 0; r < 16; ++r) { oa[0][r] *= al; oa[1][r] *= al; }
        m = mnew;
      }
      float ps = 0.f;
#pragma unroll
      for (int half = 0; half < 2; ++half)
#pragma unroll
        for (int sub = 0; sub < 2; ++sub)
#pragma unroll
          for (int r = 0; r < 16; ++r) {
            const float pv = __builtin_amdgcn_exp2f(s[half][sub][r] - m);
            s[half][sub][r] = pv;
            ps += pv;
          }
      ps += __shfl_xor(ps, 32);
      lsum += ps;

      // ---- P -> f16 fragments in-register (T12), then PV per half
#pragma unroll
      for (int half = 0; half < 2; ++half) {
        if (half == 1 && skip1) continue;
        h8_t pf[4];
        pack_pfrag((const float*)&s[half][0], pf + 0);
        pack_pfrag((const float*)&s[half][1], pf + 2);
        const char* Vb = (const char*)&Vl[cur][half][0];
        __builtin_amdgcn_s_setprio(1);
#pragma unroll
        for (int dt = 0; dt < 2; ++dt) {
#pragma unroll
          for (int kg = 0; kg < 4; ++kg) {
            const int row = dt * 32 + l31;
            const int bc = kg * 32 + hi * 16;
            h8_t vf = *(const h8_t*)(Vb + row * 128 + (bc ^ ((row & 7) << 4)));
            oa[dt] = MFMA_32x32x16_F16(vf, pf[kg], oa[dt]);
          }
        }
        __builtin_amdgcn_s_setprio(0);
      }
      __syncthreads();
    }

    const float inv = __builtin_amdgcn_rcpf(lsum);
    _Float16* Op = O + ((size_t)b * 2048 + qrow) * 1024 + h * 64;
#pragma unroll
    for (int dt = 0; dt < 2; ++dt) {
#pragma unroll
      for (int rg = 0; rg < 4; ++rg) {
        h4_t pk4;
#pragma unroll
        for (int i = 0; i < 4; ++i) pk4[i] = (_Float16)(oa[dt][rg * 4 + i] * inv);
        *reinterpret_cast<h4_t*>(Op + dt * 32 + rg * 8 + hi * 4) = pk4;
      }
    }
  }
}

extern "C" void kernel_launch(void* const* d_in, const int* in_sizes, int n_in,
                              void* d_out, int out_size, void* d_ws, size_t ws_size,
                              hipStream_t stream) {
  (void)in_sizes; (void)n_in; (void)out_size; (void)ws_size;
  const float* x = (const float*)d_in[0];
  const float* w_qkv = (const float*)d_in[1];
  const float* b_qkv = (const float*)d_in[2];
  const float* w_out = (const float*)d_in[3];
  const float* b_out = (const float*)d_in[4];
  float* out = (float*)d_out;

  char* ws = (char*)d_ws;
  size_t off = 0;
  auto alloc = [&](size_t bytes) {
    void* p = ws + off;
    off += (bytes + 255) & ~(size_t)255;
    return p;
  };
  _Float16* x16 = (_Float16*)alloc((size_t)8192 * 1024 * 2);
  _Float16* wqkvT = (_Float16*)alloc((size_t)3072 * 1024 * 2);
  _Float16* woutT = (_Float16*)alloc((size_t)1024 * 1024 * 2);
  _Float16* Qh = (_Float16*)alloc((size_t)64 * 2048 * 64 * 2);
  _Float16* Kh = (_Float16*)alloc((size_t)64 * 2048 * 64 * 2);
  _Float16* Vth = (_Float16*)alloc((size_t)64 * 64 * 2048 * 2);
  _Float16* Oh = (_Float16*)alloc((size_t)8192 * 1024 * 2);

  prep_kernel<<<8192 + 3072 + 1024, 256, 0, stream>>>(x, x16, w_qkv, wqkvT, w_out, woutT);
  gemm_qkv_kernel<<<256, 512, 0, stream>>>(x16, wqkvT, b_qkv, Qh, Kh, Vth);
  attn_kernel<<<64 * 8, 256, 0, stream>>>(Qh, Kh, Vth, Oh);
  gemm_out_kernel<<<64 * 8, 256, 0, stream>>>(Oh, woutT, b_out, out, 8);
}